// Round 5
// baseline (397.588 us; speedup 1.0000x reference)
//
#include <hip/hip_runtime.h>
#include <hip/hip_bf16.h>
#include <stdint.h>

using bf16 = __hip_bfloat16;
typedef __attribute__((ext_vector_type(8))) short   short8;
typedef __attribute__((ext_vector_type(4))) float   floatx4;

static __device__ __forceinline__ unsigned short f2bf(float f) {
    return __builtin_bit_cast(unsigned short, __float2bfloat16(f));
}

// async global->LDS, 16B per lane; lds dest = wave-uniform base + lane*16 (m97)
static __device__ __forceinline__ void gload16(const ushort* g, ushort* ldsbase) {
    __builtin_amdgcn_global_load_lds(
        (const __attribute__((address_space(1))) unsigned int*)g,
        (__attribute__((address_space(3))) unsigned int*)ldsbase, 16, 0, 0);
}

// Load 8 consecutive elements at element-offset e as 8 packed bf16.
static __device__ __forceinline__ uint4 load8bf(const void* p, size_t e, int f) {
    if (!f) return *(const uint4*)((const ushort*)p + e);
    const float* fp = (const float*)p + e;
    float4 a = *(const float4*)fp;
    float4 b = *(const float4*)(fp + 4);
    union { uint4 u; unsigned short s[8]; } r;
    r.s[0] = f2bf(a.x); r.s[1] = f2bf(a.y); r.s[2] = f2bf(a.z); r.s[3] = f2bf(a.w);
    r.s[4] = f2bf(b.x); r.s[5] = f2bf(b.y); r.s[6] = f2bf(b.z); r.s[7] = f2bf(b.w);
    return r.u;
}

static __device__ __forceinline__ float loadScalar(const void* p, int i, int f) {
    return f ? ((const float*)p)[i] : __bfloat162float(((const bf16*)p)[i]);
}

// ---------------------------------------------------------------------------
__global__ void detect_dtype(const ushort* __restrict__ x, int* __restrict__ flag) {
    __shared__ int cnt;
    if (threadIdx.x == 0) cnt = 0;
    __syncthreads();
    unsigned short u = x[threadIdx.x * 2];
    int e = (u >> 7) & 0xFF;
    int bad = (e > 133 || e < 94) ? 1 : 0;
    atomicAdd(&cnt, bad);
    __syncthreads();
    if (threadIdx.x == 0) *flag = (cnt > 64) ? 1 : 0;
}

// ---------------------------------------------------------------------------
// NT GEMM (m97 structure: bf16 path stages via global_load_lds width=16).
// pa/pb epilogue modes: 0 row-major, 1 scatter [B,H,S,D], 2 packed V^T [B,H,D,S].
// ---------------------------------------------------------------------------
__global__ __launch_bounds__(256, 2)
void gemm_bt(const void* __restrict__ A,
             const void* __restrict__ Wa, const void* __restrict__ Wb,
             const void* __restrict__ Ba, const void* __restrict__ Bb,
             void* __restrict__ Oa, void* __restrict__ Ob_,
             int pa, int pb, int a_ext, int out_ext,
             const int* __restrict__ flagp)
{
    __shared__ ushort As[128 * 32];
    __shared__ ushort Bs[128 * 32];

    const int f  = *flagp;
    const int fA = a_ext ? f : 0;
    const int z  = blockIdx.z;
    const void* W   = z ? Wb : Wa;
    const void* Bi  = z ? Bb : Ba;
    void*       Out = z ? Ob_ : Oa;
    const int   pm  = z ? pb : pa;

    const int n0 = blockIdx.x * 128;
    const int m0 = blockIdx.y * 128;
    const int tid  = threadIdx.x;
    const int lane = tid & 63;
    const int wave = tid >> 6;
    const int wm = wave >> 1, wn = wave & 1;
    const int r15  = lane & 15;
    const int quad = lane >> 4;

    floatx4 acc[4][4];
#pragma unroll
    for (int i = 0; i < 4; i++)
#pragma unroll
        for (int j = 0; j < 4; j++) acc[i][j] = (floatx4){0.f, 0.f, 0.f, 0.f};

    const ushort* A16 = (const ushort*)A;
    const ushort* W16 = (const ushort*)W;

    for (int kb = 0; kb < 1024; kb += 32) {
        if (f == 0) {
            // fast path: async 16B/lane direct-to-LDS (LDS layout = idx*16B)
#pragma unroll
            for (int p = 0; p < 2; p++) {
                int idx = tid + p * 256;
                int row = idx >> 2, kg = idx & 3;
                ushort* abase = &As[(size_t)(wave * 64 + p * 256) * 8];
                ushort* bbase = &Bs[(size_t)(wave * 64 + p * 256) * 8];
                gload16(A16 + (size_t)(m0 + row) * 1024 + kb + kg * 8, abase);
                gload16(W16 + (size_t)(n0 + row) * 1024 + kb + kg * 8, bbase);
            }
        } else {
#pragma unroll
            for (int p = 0; p < 2; p++) {
                int idx = tid + p * 256;
                int row = idx >> 2, kg = idx & 3;
                *(uint4*)(&As[(size_t)idx * 8]) =
                    load8bf(A, (size_t)(m0 + row) * 1024 + kb + kg * 8, fA);
                *(uint4*)(&Bs[(size_t)idx * 8]) =
                    load8bf(W, (size_t)(n0 + row) * 1024 + kb + kg * 8, f);
            }
        }
        __syncthreads();

        short8 af[4], bfr[4];
#pragma unroll
        for (int i = 0; i < 4; i++)
            af[i] = *(const short8*)(&As[(wm * 64 + i * 16 + r15) * 32 + quad * 8]);
#pragma unroll
        for (int j = 0; j < 4; j++)
            bfr[j] = *(const short8*)(&Bs[(wn * 64 + j * 16 + r15) * 32 + quad * 8]);

#pragma unroll
        for (int i = 0; i < 4; i++)
#pragma unroll
            for (int j = 0; j < 4; j++)
                acc[i][j] = __builtin_amdgcn_mfma_f32_16x16x32_bf16(
                    af[i], bfr[j], acc[i][j], 0, 0, 0);
        __syncthreads();
    }

    // C/D layout: col = lane&15, row = quad*4 + r (m89/m91)
#pragma unroll
    for (int i = 0; i < 4; i++) {
#pragma unroll
        for (int j = 0; j < 4; j++) {
            int col = n0 + wn * 64 + j * 16 + r15;
            float bias = loadScalar(Bi, col, f);
            if (pm == 2) {
                int h = col >> 6, d = col & 63;
                int row0 = m0 + wm * 64 + i * 16 + quad * 4;
                int b_ = row0 >> 11, s = row0 & 2047;
                union { uint2 u; ushort us[4]; } pk;
#pragma unroll
                for (int r = 0; r < 4; r++) pk.us[r] = f2bf(acc[i][j][r] + bias);
                *(uint2*)((ushort*)Out +
                          (((size_t)((b_ * 16 + h) * 64 + d)) << 11) + s) = pk.u;
            } else {
#pragma unroll
                for (int r = 0; r < 4; r++) {
                    int row = m0 + wm * 64 + i * 16 + quad * 4 + r;
                    float v = acc[i][j][r] + bias;
                    if (pm == 1) {
                        int h = col >> 6, d = col & 63;
                        int b_ = row >> 11, s = row & 2047;
                        ((ushort*)Out)[(((size_t)(b_ * 16 + h) * 2048 + s) << 6) + d]
                            = f2bf(v);
                    } else if (out_ext && f) {
                        ((float*)Out)[(size_t)row * 1024 + col] = v;
                    } else {
                        ((ushort*)Out)[(size_t)row * 1024 + col] = f2bf(v);
                    }
                }
            }
        }
    }
}

// ---------------------------------------------------------------------------
// Fused Q-projection + flash attention — 64 queries/block (16/wave), 24 KB
// LDS, grid 1024 blocks (4/CU): concurrency-first restructure.
//   Phase 1: Q = x@Wq^T + bq (single-buffered, reg-prefetched, 2 barriers/it)
//   Phase 2: per 64-key tile: S^T = K Q^T; P = 2^S (fixed-max softmax,
//     log2(e)/8 folded into Q); l via ones-MFMA; O += P V^T.  K/V^T register-
//     prefetched one tile ahead; single LDS buffer, 2 barriers/tile.
// pool (12288 ushorts): ph1 xs|wsm|Qs = [0|4096|8192]; ph2 Ks|Vt|Ps = same.
// Ps/Qs rows are own-wave (16 rows per wave) -> no extra barriers.
// ---------------------------------------------------------------------------
__global__ __launch_bounds__(256, 4)
void attn_fused(const void* __restrict__ x, const void* __restrict__ Wq,
                const void* __restrict__ bq,
                const ushort* __restrict__ K, const ushort* __restrict__ VT,
                ushort* __restrict__ AO, const int* __restrict__ flagp)
{
    __shared__ ushort pool[12288];          // 24 KB

    const int f   = *flagp;
    const int bh  = blockIdx.y;
    const int h   = bh & 15, b_ = bh >> 4;
    const int q0  = blockIdx.x * 64;
    const int tid  = threadIdx.x;
    const int lane = tid & 63;
    const int wave = tid >> 6;
    const int r15  = lane & 15;
    const int quad = lane >> 4;
    const size_t base = (size_t)bh << 17;

    const int srow = tid >> 3;              // staging row 0..31 (+p*32)
    const int sg   = tid & 7;               // staging 8-elem group

    // ---- early prefetch: flash tile 0 (latency hidden under phase 1) ----
    uint4 kpre[2], vpre[2];
#pragma unroll
    for (int p = 0; p < 2; p++) {
        int row = srow + p * 32;
        kpre[p] = *(const uint4*)(K  + base + (size_t)row * 64   + sg * 8);
        vpre[p] = *(const uint4*)(VT + base + (size_t)row * 2048 + sg * 8);
    }

    // ---------------- Phase 1: Q tile (64 q x 64 d) ----------------
    ushort* xs  = pool;
    ushort* wsm = pool + 4096;
    floatx4 qacc[4];
#pragma unroll
    for (int db = 0; db < 4; db++) qacc[db] = (floatx4){0.f,0.f,0.f,0.f};

    uint4 xpre[2], wpre[2];
#pragma unroll
    for (int p = 0; p < 2; p++) {
        int row = srow + p * 32;
        xpre[p] = load8bf(x, (size_t)(b_ * 2048 + q0 + row) * 1024 + sg * 8, f);
        wpre[p] = load8bf(Wq, (size_t)(h * 64 + row) * 1024 + sg * 8, f);
    }

    for (int kb = 0; kb < 1024; kb += 64) {
#pragma unroll
        for (int p = 0; p < 2; p++) {
            int row = srow + p * 32;
            *(uint4*)(&xs [row * 64 + ((sg ^ (row & 7)) << 3)]) = xpre[p];
            *(uint4*)(&wsm[row * 64 + ((sg ^ (row & 7)) << 3)]) = wpre[p];
        }
        __syncthreads();
        if (kb + 64 < 1024) {
#pragma unroll
            for (int p = 0; p < 2; p++) {
                int row = srow + p * 32;
                xpre[p] = load8bf(x, (size_t)(b_ * 2048 + q0 + row) * 1024
                                      + kb + 64 + sg * 8, f);
                wpre[p] = load8bf(Wq, (size_t)(h * 64 + row) * 1024
                                       + kb + 64 + sg * 8, f);
            }
        }
#pragma unroll
        for (int ks = 0; ks < 2; ks++) {
            int arow = wave * 16 + r15;
            short8 af = *(const short8*)(
                &xs[arow * 64 + (((ks * 4 + quad) ^ (arow & 7)) << 3)]);
#pragma unroll
            for (int db = 0; db < 4; db++) {
                int brow = db * 16 + r15;
                short8 bv = *(const short8*)(
                    &wsm[brow * 64 + (((ks * 4 + quad) ^ (brow & 7)) << 3)]);
                qacc[db] = __builtin_amdgcn_mfma_f32_16x16x32_bf16(
                    af, bv, qacc[db], 0, 0, 0);
            }
        }
        __syncthreads();
    }

    // Qs = pool+8192 (own-wave rows); bias + log2(e)/8 scale
    ushort* Qs = pool + 8192;
    const float csc = 0.1803368801f;
#pragma unroll
    for (int db = 0; db < 4; db++) {
        int d = db * 16 + r15;
        float bias = loadScalar(bq, h * 64 + d, f);
#pragma unroll
        for (int r = 0; r < 4; r++) {
            int q = wave * 16 + quad * 4 + r;
            Qs[q * 64 + (((d >> 3) ^ (q & 7)) << 3) + (d & 7)] =
                f2bf((qacc[db][r] + bias) * csc);
        }
    }
    short8 qf[2];
#pragma unroll
    for (int ks = 0; ks < 2; ks++) {
        int arow = wave * 16 + r15;
        qf[ks] = *(const short8*)(
            &Qs[arow * 64 + (((ks * 4 + quad) ^ (arow & 7)) << 3)]);
    }

    // ---------------- Phase 2: flash loop ----------------
    ushort* Ks = pool;
    ushort* Vt = pool + 4096;
    ushort* Ps = pool + 8192;
    floatx4 oacc[4], lacc;
#pragma unroll
    for (int db = 0; db < 4; db++) oacc[db] = (floatx4){0.f,0.f,0.f,0.f};
    lacc = (floatx4){0.f,0.f,0.f,0.f};
    short8 ones;
#pragma unroll
    for (int j = 0; j < 8; j++) ones[j] = (short)0x3F80;   // bf16 1.0

    for (int t0 = 0; t0 < 2048; t0 += 64) {
#pragma unroll
        for (int p = 0; p < 2; p++) {
            int row = srow + p * 32;
            *(uint4*)(&Ks[row * 64 + ((sg ^ (row & 7)) << 3)]) = kpre[p];
            *(uint4*)(&Vt[row * 64 + ((sg ^ (row & 7)) << 3)]) = vpre[p];
        }
        __syncthreads();
        if (t0 < 1984) {
#pragma unroll
            for (int p = 0; p < 2; p++) {
                int row = srow + p * 32;
                kpre[p] = *(const uint4*)(K  + base + (size_t)(t0 + 64 + row) * 64
                                              + sg * 8);
                vpre[p] = *(const uint4*)(VT + base + (size_t)row * 2048
                                              + t0 + 64 + sg * 8);
            }
        }

        // S^T = K Q^T : rows = keys (m), col = query (n)
        floatx4 s[4];
#pragma unroll
        for (int mb = 0; mb < 4; mb++) s[mb] = (floatx4){0.f,0.f,0.f,0.f};
#pragma unroll
        for (int ks = 0; ks < 2; ks++)
#pragma unroll
            for (int mb = 0; mb < 4; mb++) {
                int arow = mb * 16 + r15;
                short8 kf = *(const short8*)(
                    &Ks[arow * 64 + (((ks * 4 + quad) ^ (arow & 7)) << 3)]);
                s[mb] = __builtin_amdgcn_mfma_f32_16x16x32_bf16(
                    kf, qf[ks], s[mb], 0, 0, 0);
            }

        // P = 2^S, truncation-packed pairs -> own-wave b64 writes
#pragma unroll
        for (int mb = 0; mb < 4; mb++) {
            int q  = wave * 16 + r15;
            int tg = (mb * 4 + quad) ^ ((q & 7) << 1);
            uint b0 = __builtin_bit_cast(uint, __builtin_amdgcn_exp2f(s[mb][0]));
            uint b1 = __builtin_bit_cast(uint, __builtin_amdgcn_exp2f(s[mb][1]));
            uint b2 = __builtin_bit_cast(uint, __builtin_amdgcn_exp2f(s[mb][2]));
            uint b3 = __builtin_bit_cast(uint, __builtin_amdgcn_exp2f(s[mb][3]));
            uint2 pk;
            pk.x = (b1 & 0xFFFF0000u) | (b0 >> 16);
            pk.y = (b3 & 0xFFFF0000u) | (b2 >> 16);
            *(uint2*)(&Ps[q * 64 + tg * 4]) = pk;
        }

        // O += P V^T, l += P·1
#pragma unroll
        for (int ks2 = 0; ks2 < 2; ks2++) {
            int q   = wave * 16 + r15;
            int tg0 = (ks2 * 8 + quad * 2) ^ ((q & 7) << 1);
            short8 pf = *(const short8*)(&Ps[q * 64 + tg0 * 4]);
#pragma unroll
            for (int db = 0; db < 4; db++) {
                int brow = db * 16 + r15;
                short8 vf = *(const short8*)(
                    &Vt[brow * 64 + (((ks2 * 4 + quad) ^ (brow & 7)) << 3)]);
                oacc[db] = __builtin_amdgcn_mfma_f32_16x16x32_bf16(
                    pf, vf, oacc[db], 0, 0, 0);
            }
            lacc = __builtin_amdgcn_mfma_f32_16x16x32_bf16(
                pf, ones, lacc, 0, 0, 0);
        }
        __syncthreads();
    }

    // ---- epilogue: O / l -> AO [B,S,1024] bf16 staging ----
    float inv[4];
#pragma unroll
    for (int r = 0; r < 4; r++) inv[r] = 1.f / lacc[r];
#pragma unroll
    for (int db = 0; db < 4; db++) {
        int d = db * 16 + r15;
#pragma unroll
        for (int r = 0; r < 4; r++) {
            int qi = q0 + wave * 16 + quad * 4 + r;
            AO[((size_t)(b_ * 2048 + qi) << 10) + h * 64 + d] =
                f2bf(oacc[db][r] * inv[r]);
        }
    }
}

__global__ void copy_u4(const uint4* __restrict__ src, uint4* __restrict__ dst) {
    size_t i = (size_t)blockIdx.x * 256 + threadIdx.x;
    dst[i] = src[i];
}

// ---------------------------------------------------------------------------
extern "C" void kernel_launch(void* const* d_in, const int* in_sizes, int n_in,
                              void* d_out, int out_size, void* d_ws, size_t ws_size,
                              hipStream_t stream)
{
    const void* x  = d_in[0];
    const void* Wq = d_in[1];
    const void* bq = d_in[2];
    const void* Wk = d_in[3];
    const void* bk = d_in[4];
    const void* Wv = d_in[5];
    const void* bv = d_in[6];
    const void* Wo = d_in[7];
    const void* bo = d_in[8];

    // ws: [flag, pad 256B][Kw 8MB][Vw(V^T) 8MB].  Obuf reuses Kw after attn.
    int*    flagp = (int*)d_ws;
    ushort* Kw    = (ushort*)((char*)d_ws + 256);
    ushort* Vw    = Kw + (size_t)2 * 16 * 2048 * 64;
    ushort* Obuf  = Kw;

    dim3 blk(256);
    detect_dtype<<<1, 256, 0, stream>>>((const ushort*)x, flagp);

    // K -> Kw [B,H,S,D] (pm=1);  V -> Vw [B,H,D,S] directly (pm=2)
    gemm_bt<<<dim3(8, 32, 2), blk, 0, stream>>>(
        x, Wk, Wv, bk, bv, Kw, Vw, /*pa=*/1, /*pb=*/2, /*a_ext=*/1,
        /*out_ext=*/0, flagp);

    // fused Q-proj + attention -> AO staged in d_out (bf16 [B,S,1024])
    attn_fused<<<dim3(32, 32), blk, 0, stream>>>(
        x, Wq, bq, Kw, Vw, (ushort*)d_out, flagp);

    // move AO out of d_out so the O-projection is race-free
    copy_u4<<<dim3(2048), blk, 0, stream>>>((const uint4*)d_out, (uint4*)Obuf);

    // O-projection -> final output (dtype per flag)
    gemm_bt<<<dim3(8, 32, 1), blk, 0, stream>>>(
        Obuf, Wo, Wo, bo, bo, d_out, d_out, /*pa=*/0, /*pb=*/0, /*a_ext=*/0,
        /*out_ext=*/1, flagp);
}